// Round 16
// baseline (375.509 us; speedup 1.0000x reference)
//
#include <hip/hip_runtime.h>
#include <hip/hip_bf16.h>

// ---------------------------------------------------------------------------
// WindowsMultiheadAttention: 4096 windows x (L=49, E=256), 8 heads x d=32.
// R16 = R15 (364 us) + placement changes at fixed structure:
//  - mid-loop barrier moved to right after all Qb/Kb/VTb READS (vb hoisted):
//    the long attention tail (exp/E/ones-MFMA/PV/ob) + next-hp QKV become one
//    barrier-free segment (same barrier count, longer unsynced stretch).
//  - out-projection: 4 concurrent nt-chains (pacc/pv dead there; ~108 VGPR).
// ---------------------------------------------------------------------------

typedef float  f32x4  __attribute__((ext_vector_type(4)));
typedef short  s16x8  __attribute__((ext_vector_type(8)));
typedef short  s16x4  __attribute__((ext_vector_type(4)));

#define MFMA16(a, b, c) __builtin_amdgcn_mfma_f32_16x16x32_bf16((a), (b), (c), 0, 0, 0)

static __device__ __forceinline__ unsigned short f2bf(float f) {
    __hip_bfloat16 h = __float2bfloat16(f);
    unsigned short u;
    __builtin_memcpy(&u, &h, 2);
    return u;
}

// ---- LDS layout (bytes) ----------------------------------------------------
// winb/ob [64][264] bf16 @ 0      (33792)
// Qb      [64][72]  bf16 @ 33792  (9216)
// Kb      [64][72]  bf16 @ 43008  (9216)
// VTb     [64][72]  bf16 @ 52224  (9216)
// Pw      [4][32][72] bf16 @ 61440 (18432)   per-wave private (unnormalized E)
// stg     [64][66]  f32  @ 33792  (16896)    overlays dead Q/K at END
#define SMEM_BYTES 79872
#define WS 264
#define QS 72

__global__ __launch_bounds__(256, 2)
void wmha_fused_kernel(const float* __restrict__ x,
                       const float* __restrict__ bqkv,
                       const float* __restrict__ bout,
                       const unsigned short* __restrict__ wq,   // [768][256] bf16
                       const unsigned short* __restrict__ wo,   // [256][256] bf16
                       float* __restrict__ yout,                // [4096][49][256]
                       float* __restrict__ aout)                // [4096][49][49]
{
    extern __shared__ char smem[];
    unsigned short* winb = (unsigned short*)smem;             // [64][264], later ob
    unsigned short* Qb   = (unsigned short*)(smem + 33792);   // [64][72]
    unsigned short* Kb   = (unsigned short*)(smem + 43008);   // [64][72]
    unsigned short* VTb  = (unsigned short*)(smem + 52224);   // [64][72]
    float* stg = (float*)(smem + 33792);                      // [64][66] f32 (end)

    const int tid  = threadIdx.x;
    const int wave = tid >> 6;
    const int lane = tid & 63;
    const int lx   = lane & 15;
    const int lg   = lane >> 4;
    const int h    = wave & 1;    // head within pair
    const int mh   = wave >> 1;   // M half

    unsigned short* Pw = (unsigned short*)(smem + 61440 + wave * 4608); // [32][72]

    const int m  = blockIdx.x;
    const int b  = m >> 6;
    const int w  = m & 63;
    const int hk = w >> 3;
    const int wk = w & 7;
    const float* xb = x + (size_t)b * 3136 * 256;

    // ---- gather window into LDS (scramble); compile-time unrolled ----------
    #pragma unroll
    for (int ii = 0; ii < 13; ++ii) {
        const int k = tid + ii * 256;
        if (k < 3136) {
            const int p  = k >> 6;
            const int l4 = (k & 63) * 4;
            const int ky = p / 7, kx = p - ky * 7;
            const int rimg = (hk * 7 + ky) * 56 + wk * 7 + kx;
            const float4 v = *(const float4*)&xb[rimg * 256 + l4];
            #pragma unroll
            for (int e = 0; e < 4; ++e) {
                const int j = (l4 + e) * 49 + p;   // l*256+c == c'*49+p
                winb[(j >> 8) * WS + (j & 255)] =
                    f2bf(e == 0 ? v.x : e == 1 ? v.y : e == 2 ? v.z : v.w);
            }
        }
    }
    // zero pad rows 49..63 (vectorized b64)
    #pragma unroll
    for (int ii = 0; ii < 4; ++ii) {
        const int i = tid + ii * 256;         // 960 total
        if (i < 960) {
            const int row = 49 + (i >> 6);
            const int c4  = (i & 63) * 4;
            *(s16x4*)&winb[row * WS + c4] = (s16x4){0, 0, 0, 0};
        }
    }
    __syncthreads();   // b1

    // ---- cache win A-fragments in registers (128 regs) ---------------------
    s16x8 afrag[4][8];
    #pragma unroll
    for (int mt = 0; mt < 4; ++mt)
        #pragma unroll
        for (int ks = 0; ks < 8; ++ks)
            afrag[mt][ks] = *(const s16x8*)&winb[(lx + mt * 16) * WS + ks * 32 + lg * 8];
    __syncthreads();   // b2: winb dead -> region becomes ob

    unsigned short* ob = winb;
    const float scale = 0.17677669529663687f;     // 1/sqrt(32)
    float pacc[2][4][4] = {};                     // [mt][r][nt] attn-mean accum

    // bf16 ones B-fragment for row-sum MFMA (1.0 = 0x3F80)
    s16x8 onesf;
    #pragma unroll
    for (int j = 0; j < 8; ++j) onesf[j] = (short)0x3F80;

    #pragma unroll 1
    for (int hp = 0; hp < 4; ++hp) {
        // ---- QKV projection: this wave's 3 n-tiles (of 12), tile-serial ----
        // (safe without a preceding barrier: the previous iteration's tail
        //  touches only Pw/regs/ob, never Qb/Kb/VTb; all Q/K/VT reads were
        //  barriered at b_mid of the previous iteration.)
        #pragma unroll
        for (int i = 0; i < 3; ++i) {
            const int t = wave * 3 + i;
            const int part = t >> 2;              // 0=Q 1=K 2=V
            const int sub  = t & 3;               // 16-col chunk of 64-col pair
            const int n0 = part * 256 + hp * 64 + sub * 16;
            f32x4 acc[4] = {};
            const unsigned short* wp = wq + (size_t)(n0 + lx) * 256 + lg * 8;
            #pragma unroll
            for (int ks = 0; ks < 8; ++ks) {
                const s16x8 bb = *(const s16x8*)(wp + ks * 32);
                #pragma unroll
                for (int mt = 0; mt < 4; ++mt)
                    acc[mt] = MFMA16(afrag[mt][ks], bb, acc[mt]);
            }
            const float bias = bqkv[n0 + lx];
            if (part == 0) {
                #pragma unroll
                for (int mt = 0; mt < 4; ++mt)
                    #pragma unroll
                    for (int r = 0; r < 4; ++r)
                        Qb[(mt * 16 + lg * 4 + r) * QS + sub * 16 + lx] =
                            f2bf((acc[mt][r] + bias) * scale);   // pre-scaled Q
            } else if (part == 1) {
                #pragma unroll
                for (int mt = 0; mt < 4; ++mt)
                    #pragma unroll
                    for (int r = 0; r < 4; ++r)
                        Kb[(mt * 16 + lg * 4 + r) * QS + sub * 16 + lx] =
                            f2bf(acc[mt][r] + bias);
            } else {
                #pragma unroll
                for (int mt = 0; mt < 4; ++mt) {  // V^T, packed b64 over tokens
                    s16x4 pk;
                    #pragma unroll
                    for (int r = 0; r < 4; ++r)
                        pk[r] = (short)f2bf(acc[mt][r] + bias);
                    *(s16x4*)&VTb[(sub * 16 + lx) * QS + mt * 16 + lg * 4] = pk;
                }
            }
        }
        __syncthreads();   // b_hp1: Q/K/VT ready

        // ---- ALL Q/K/VT reads happen here, then barrier --------------------
        s16x8 qa[2];
        #pragma unroll
        for (int mt = 0; mt < 2; ++mt)
            qa[mt] = *(const s16x8*)&Qb[(mh * 32 + mt * 16 + lx) * QS + h * 32 + lg * 8];
        f32x4 sacc[2][4] = {};
        #pragma unroll
        for (int nt = 0; nt < 4; ++nt) {
            const s16x8 kb = *(const s16x8*)&Kb[(nt * 16 + lx) * QS + h * 32 + lg * 8];
            #pragma unroll
            for (int mt = 0; mt < 2; ++mt)
                sacc[mt][nt] = MFMA16(qa[mt], kb, sacc[mt][nt]);
        }
        s16x8 vb[2][2];
        #pragma unroll
        for (int nt = 0; nt < 2; ++nt)
            #pragma unroll
            for (int ks = 0; ks < 2; ++ks)
                vb[nt][ks] = *(const s16x8*)&VTb[(h * 32 + nt * 16 + lx) * QS + ks * 32 + lg * 8];
        __syncthreads();   // b_mid: all shared reads done; tail + next QKV free-run

        // ---- exp only (no shuffles); E stays UNNORMALIZED ------------------
        float pv[2][4][4];
        #pragma unroll
        for (int mt = 0; mt < 2; ++mt) {
            #pragma unroll
            for (int r = 0; r < 4; ++r) {
                const bool ok3 = (lx == 0);       // col 48+lx valid iff lx==0
                pv[mt][r][0] = __expf(sacc[mt][0][r]);
                pv[mt][r][1] = __expf(sacc[mt][1][r]);
                pv[mt][r][2] = __expf(sacc[mt][2][r]);
                pv[mt][r][3] = ok3 ? __expf(sacc[mt][3][r]) : 0.f;
            }
        }

        // ---- write unnormalized E to PRIVATE buffer (no barrier) -----------
        #pragma unroll
        for (int mt = 0; mt < 2; ++mt)
            #pragma unroll
            for (int r = 0; r < 4; ++r) {
                const int qr = mt * 16 + lg * 4 + r;   // local row 0..31
                #pragma unroll
                for (int nt = 0; nt < 4; ++nt)
                    Pw[qr * QS + nt * 16 + lx] = f2bf(pv[mt][r][nt]);
            }

        // ---- read E fragments; row-sums via ones-MFMA ----------------------
        s16x8 pa[2][2];
        #pragma unroll
        for (int mt = 0; mt < 2; ++mt)
            #pragma unroll
            for (int ks = 0; ks < 2; ++ks)
                pa[mt][ks] = *(const s16x8*)&Pw[(mt * 16 + lx) * QS + ks * 32 + lg * 8];
        f32x4 ssum[2] = {};
        #pragma unroll
        for (int ks = 0; ks < 2; ++ks)
            #pragma unroll
            for (int mt = 0; mt < 2; ++mt)
                ssum[mt] = MFMA16(pa[mt][ks], onesf, ssum[mt]);
        float invv[2][4];
        #pragma unroll
        for (int mt = 0; mt < 2; ++mt)
            #pragma unroll
            for (int r = 0; r < 4; ++r) {
                invv[mt][r] = 1.0f / ssum[mt][r];
                const float w8 = invv[mt][r] * 0.125f;
                #pragma unroll
                for (int nt = 0; nt < 4; ++nt)
                    pacc[mt][r][nt] += pv[mt][r][nt] * w8;
            }

        // ---- PV: o = (E V) * inv (vb pre-read) -----------------------------
        f32x4 oacc[2][2] = {};
        #pragma unroll
        for (int ks = 0; ks < 2; ++ks)
            #pragma unroll
            for (int mt = 0; mt < 2; ++mt)
                #pragma unroll
                for (int nt = 0; nt < 2; ++nt)
                    oacc[mt][nt] = MFMA16(pa[mt][ks], vb[nt][ks], oacc[mt][nt]);
        #pragma unroll
        for (int mt = 0; mt < 2; ++mt)
            #pragma unroll
            for (int nt = 0; nt < 2; ++nt)
                #pragma unroll
                for (int r = 0; r < 4; ++r)
                    ob[(mh * 32 + mt * 16 + lg * 4 + r) * WS +
                       hp * 64 + h * 32 + nt * 16 + lx] =
                        f2bf(oacc[mt][nt][r] * invv[mt][r]);
        // no end-of-iteration barrier: next QKV writes Q/K/VT, whose reads
        // were all completed before b_mid; tail writes touch Pw/ob only.
    }

    // ---- attn-mean: h0 waves stage into dead Q/K region --------------------
    if (h == 0) {
        #pragma unroll
        for (int mt = 0; mt < 2; ++mt)
            #pragma unroll
            for (int r = 0; r < 4; ++r) {
                const int row = mh * 32 + mt * 16 + lg * 4 + r;
                #pragma unroll
                for (int nt = 0; nt < 4; ++nt)
                    stg[row * 66 + nt * 16 + lx] = pacc[mt][r][nt];
            }
    }
    __syncthreads();   // b_stg: ob complete (all tails) + stg visible

    // reload afrag from o (winb region)
    #pragma unroll
    for (int mt = 0; mt < 4; ++mt)
        #pragma unroll
        for (int ks = 0; ks < 8; ++ks)
            afrag[mt][ks] = *(const s16x8*)&ob[(lx + mt * 16) * WS + ks * 32 + lg * 8];

    // ---- h1 waves combine + store attention-mean ---------------------------
    if (h == 1) {
        float* abase = aout + (size_t)m * 2401;
        #pragma unroll
        for (int mt = 0; mt < 2; ++mt)
            #pragma unroll
            for (int r = 0; r < 4; ++r) {
                const int q = mh * 32 + mt * 16 + lg * 4 + r;
                if (q < 49) {
                    #pragma unroll
                    for (int nt = 0; nt < 4; ++nt) {
                        const int col = nt * 16 + lx;
                        if (col < 49)
                            abase[q * 49 + col] = stg[q * 66 + col] + pacc[mt][r][nt];
                    }
                }
            }
    }

    // ---- out projection: 4 concurrent nt-chains (pacc/pv dead here) --------
    float* ybase = yout + (size_t)m * 12544;
    {
        const int n0 = wave * 64;
        const unsigned short* wp0 = wo + (size_t)(n0 +  0 + lx) * 256 + lg * 8;
        const unsigned short* wp1 = wo + (size_t)(n0 + 16 + lx) * 256 + lg * 8;
        const unsigned short* wp2 = wo + (size_t)(n0 + 32 + lx) * 256 + lg * 8;
        const unsigned short* wp3 = wo + (size_t)(n0 + 48 + lx) * 256 + lg * 8;
        f32x4 a0[4] = {}, a1[4] = {}, a2[4] = {}, a3[4] = {};
        #pragma unroll
        for (int ks = 0; ks < 8; ++ks) {
            const s16x8 b0 = *(const s16x8*)(wp0 + ks * 32);
            const s16x8 b1 = *(const s16x8*)(wp1 + ks * 32);
            const s16x8 b2 = *(const s16x8*)(wp2 + ks * 32);
            const s16x8 b3 = *(const s16x8*)(wp3 + ks * 32);
            #pragma unroll
            for (int mt = 0; mt < 4; ++mt) {
                a0[mt] = MFMA16(afrag[mt][ks], b0, a0[mt]);
                a1[mt] = MFMA16(afrag[mt][ks], b1, a1[mt]);
                a2[mt] = MFMA16(afrag[mt][ks], b2, a2[mt]);
                a3[mt] = MFMA16(afrag[mt][ks], b3, a3[mt]);
            }
        }
        const float bias0 = bout[n0 +  0 + lx];
        const float bias1 = bout[n0 + 16 + lx];
        const float bias2 = bout[n0 + 32 + lx];
        const float bias3 = bout[n0 + 48 + lx];
        #pragma unroll
        for (int mt = 0; mt < 4; ++mt) {
            #pragma unroll
            for (int r = 0; r < 4; ++r) {
                const int q = mt * 16 + lg * 4 + r;
                if (q < 49) {
                    ybase[q * 256 + n0 +  0 + lx] = a0[mt][r] + bias0;
                    ybase[q * 256 + n0 + 16 + lx] = a1[mt][r] + bias1;
                    ybase[q * 256 + n0 + 32 + lx] = a2[mt][r] + bias2;
                    ybase[q * 256 + n0 + 48 + lx] = a3[mt][r] + bias3;
                }
            }
        }
    }
}

// ---- weight conversion fp32 -> bf16 ---------------------------------------
__global__ void wmha_cvt_kernel(const float* __restrict__ w_in,
                                const float* __restrict__ w_out,
                                unsigned short* __restrict__ dq,
                                unsigned short* __restrict__ dw)
{
    const int idx = blockIdx.x * 256 + threadIdx.x;
    if (idx < 196608)      dq[idx] = f2bf(w_in[idx]);
    else                   dw[idx - 196608] = f2bf(w_out[idx - 196608]);
}

extern "C" void kernel_launch(void* const* d_in, const int* in_sizes, int n_in,
                              void* d_out, int out_size, void* d_ws, size_t ws_size,
                              hipStream_t stream) {
    const float* x    = (const float*)d_in[0];
    const float* w_in = (const float*)d_in[1];
    const float* b_in = (const float*)d_in[2];
    const float* w_o  = (const float*)d_in[3];
    const float* b_o  = (const float*)d_in[4];

    unsigned short* wq_bf = (unsigned short*)d_ws;
    unsigned short* wo_bf = wq_bf + 196608;

    float* y  = (float*)d_out;
    float* aw = y + (size_t)4096 * 49 * 256;   // 51380224

    wmha_cvt_kernel<<<1024, 256, 0, stream>>>(w_in, w_o, wq_bf, wo_bf);

    hipFuncSetAttribute((const void*)wmha_fused_kernel,
                        hipFuncAttributeMaxDynamicSharedMemorySize, SMEM_BYTES);
    wmha_fused_kernel<<<4096, 256, SMEM_BYTES, stream>>>(
        x, b_in, b_o, wq_bf, wo_bf, y, aw);
}

// Round 17
// 356.911 us; speedup vs baseline: 1.0521x; 1.0521x over previous
//
#include <hip/hip_runtime.h>
#include <hip/hip_bf16.h>

// ---------------------------------------------------------------------------
// WindowsMultiheadAttention: 4096 windows x (L=49, E=256), 8 heads x d=32.
// R17 = R15 (best: 364 us) + 4-chain out-projection ONLY.
// R16's regression attributed to the vb-hoist (extended 32-reg liveness across
// the exp phase -> ~12-reg spill); the 4-chain out-proj is register-clean at
// its site (pacc/pv/sacc dead: ~110 live VGPR + 128 afrag AGPR <= 256).
// Everything else byte-identical to R15.
// ---------------------------------------------------------------------------

typedef float  f32x4  __attribute__((ext_vector_type(4)));
typedef short  s16x8  __attribute__((ext_vector_type(8)));
typedef short  s16x4  __attribute__((ext_vector_type(4)));

#define MFMA16(a, b, c) __builtin_amdgcn_mfma_f32_16x16x32_bf16((a), (b), (c), 0, 0, 0)

static __device__ __forceinline__ unsigned short f2bf(float f) {
    __hip_bfloat16 h = __float2bfloat16(f);
    unsigned short u;
    __builtin_memcpy(&u, &h, 2);
    return u;
}

// ---- LDS layout (bytes) ----------------------------------------------------
// winb/ob [64][264] bf16 @ 0      (33792)
// Qb      [64][72]  bf16 @ 33792  (9216)
// Kb      [64][72]  bf16 @ 43008  (9216)
// VTb     [64][72]  bf16 @ 52224  (9216)
// Pw      [4][32][72] bf16 @ 61440 (18432)   per-wave private (unnormalized E)
// stg     [64][66]  f32  @ 33792  (16896)    overlays dead Q/K at END
#define SMEM_BYTES 79872
#define WS 264
#define QS 72

__global__ __launch_bounds__(256, 2)
void wmha_fused_kernel(const float* __restrict__ x,
                       const float* __restrict__ bqkv,
                       const float* __restrict__ bout,
                       const unsigned short* __restrict__ wq,   // [768][256] bf16
                       const unsigned short* __restrict__ wo,   // [256][256] bf16
                       float* __restrict__ yout,                // [4096][49][256]
                       float* __restrict__ aout)                // [4096][49][49]
{
    extern __shared__ char smem[];
    unsigned short* winb = (unsigned short*)smem;             // [64][264], later ob
    unsigned short* Qb   = (unsigned short*)(smem + 33792);   // [64][72]
    unsigned short* Kb   = (unsigned short*)(smem + 43008);   // [64][72]
    unsigned short* VTb  = (unsigned short*)(smem + 52224);   // [64][72]
    float* stg = (float*)(smem + 33792);                      // [64][66] f32 (end)

    const int tid  = threadIdx.x;
    const int wave = tid >> 6;
    const int lane = tid & 63;
    const int lx   = lane & 15;
    const int lg   = lane >> 4;
    const int h    = wave & 1;    // head within pair
    const int mh   = wave >> 1;   // M half

    unsigned short* Pw = (unsigned short*)(smem + 61440 + wave * 4608); // [32][72]

    const int m  = blockIdx.x;
    const int b  = m >> 6;
    const int w  = m & 63;
    const int hk = w >> 3;
    const int wk = w & 7;
    const float* xb = x + (size_t)b * 3136 * 256;

    // ---- gather window into LDS (scramble); compile-time unrolled ----------
    #pragma unroll
    for (int ii = 0; ii < 13; ++ii) {
        const int k = tid + ii * 256;
        if (k < 3136) {
            const int p  = k >> 6;
            const int l4 = (k & 63) * 4;
            const int ky = p / 7, kx = p - ky * 7;
            const int rimg = (hk * 7 + ky) * 56 + wk * 7 + kx;
            const float4 v = *(const float4*)&xb[rimg * 256 + l4];
            #pragma unroll
            for (int e = 0; e < 4; ++e) {
                const int j = (l4 + e) * 49 + p;   // l*256+c == c'*49+p
                winb[(j >> 8) * WS + (j & 255)] =
                    f2bf(e == 0 ? v.x : e == 1 ? v.y : e == 2 ? v.z : v.w);
            }
        }
    }
    // zero pad rows 49..63 (vectorized b64)
    #pragma unroll
    for (int ii = 0; ii < 4; ++ii) {
        const int i = tid + ii * 256;         // 960 total
        if (i < 960) {
            const int row = 49 + (i >> 6);
            const int c4  = (i & 63) * 4;
            *(s16x4*)&winb[row * WS + c4] = (s16x4){0, 0, 0, 0};
        }
    }
    __syncthreads();   // b1

    // ---- cache win A-fragments in registers (128 regs) ---------------------
    s16x8 afrag[4][8];
    #pragma unroll
    for (int mt = 0; mt < 4; ++mt)
        #pragma unroll
        for (int ks = 0; ks < 8; ++ks)
            afrag[mt][ks] = *(const s16x8*)&winb[(lx + mt * 16) * WS + ks * 32 + lg * 8];
    __syncthreads();   // b2: winb dead -> region becomes ob

    unsigned short* ob = winb;
    const float scale = 0.17677669529663687f;     // 1/sqrt(32)
    float pacc[2][4][4] = {};                     // [mt][r][nt] attn-mean accum

    // bf16 ones B-fragment for row-sum MFMA (1.0 = 0x3F80)
    s16x8 onesf;
    #pragma unroll
    for (int j = 0; j < 8; ++j) onesf[j] = (short)0x3F80;

    #pragma unroll 1
    for (int hp = 0; hp < 4; ++hp) {
        // ---- QKV projection: this wave's 3 n-tiles (of 12), tile-serial ----
        #pragma unroll
        for (int i = 0; i < 3; ++i) {
            const int t = wave * 3 + i;
            const int part = t >> 2;              // 0=Q 1=K 2=V
            const int sub  = t & 3;               // 16-col chunk of 64-col pair
            const int n0 = part * 256 + hp * 64 + sub * 16;
            f32x4 acc[4] = {};
            const unsigned short* wp = wq + (size_t)(n0 + lx) * 256 + lg * 8;
            #pragma unroll
            for (int ks = 0; ks < 8; ++ks) {
                const s16x8 bb = *(const s16x8*)(wp + ks * 32);
                #pragma unroll
                for (int mt = 0; mt < 4; ++mt)
                    acc[mt] = MFMA16(afrag[mt][ks], bb, acc[mt]);
            }
            const float bias = bqkv[n0 + lx];
            if (part == 0) {
                #pragma unroll
                for (int mt = 0; mt < 4; ++mt)
                    #pragma unroll
                    for (int r = 0; r < 4; ++r)
                        Qb[(mt * 16 + lg * 4 + r) * QS + sub * 16 + lx] =
                            f2bf((acc[mt][r] + bias) * scale);   // pre-scaled Q
            } else if (part == 1) {
                #pragma unroll
                for (int mt = 0; mt < 4; ++mt)
                    #pragma unroll
                    for (int r = 0; r < 4; ++r)
                        Kb[(mt * 16 + lg * 4 + r) * QS + sub * 16 + lx] =
                            f2bf(acc[mt][r] + bias);
            } else {
                #pragma unroll
                for (int mt = 0; mt < 4; ++mt) {  // V^T, packed b64 over tokens
                    s16x4 pk;
                    #pragma unroll
                    for (int r = 0; r < 4; ++r)
                        pk[r] = (short)f2bf(acc[mt][r] + bias);
                    *(s16x4*)&VTb[(sub * 16 + lx) * QS + mt * 16 + lg * 4] = pk;
                }
            }
        }
        __syncthreads();   // b_hp1: Q/K/VT ready

        // ---- scores = (Q*s) K^T for (head h, rows mh*32..+31) --------------
        s16x8 qa[2];
        #pragma unroll
        for (int mt = 0; mt < 2; ++mt)
            qa[mt] = *(const s16x8*)&Qb[(mh * 32 + mt * 16 + lx) * QS + h * 32 + lg * 8];
        f32x4 sacc[2][4] = {};
        #pragma unroll
        for (int nt = 0; nt < 4; ++nt) {
            const s16x8 kb = *(const s16x8*)&Kb[(nt * 16 + lx) * QS + h * 32 + lg * 8];
            #pragma unroll
            for (int mt = 0; mt < 2; ++mt)
                sacc[mt][nt] = MFMA16(qa[mt], kb, sacc[mt][nt]);
        }

        // ---- exp only (no shuffles); E stays UNNORMALIZED ------------------
        float pv[2][4][4];
        #pragma unroll
        for (int mt = 0; mt < 2; ++mt) {
            #pragma unroll
            for (int r = 0; r < 4; ++r) {
                const bool ok3 = (lx == 0);       // col 48+lx valid iff lx==0
                pv[mt][r][0] = __expf(sacc[mt][0][r]);
                pv[mt][r][1] = __expf(sacc[mt][1][r]);
                pv[mt][r][2] = __expf(sacc[mt][2][r]);
                pv[mt][r][3] = ok3 ? __expf(sacc[mt][3][r]) : 0.f;
            }
        }

        // ---- write unnormalized E to PRIVATE buffer (no barrier) -----------
        #pragma unroll
        for (int mt = 0; mt < 2; ++mt)
            #pragma unroll
            for (int r = 0; r < 4; ++r) {
                const int qr = mt * 16 + lg * 4 + r;   // local row 0..31
                #pragma unroll
                for (int nt = 0; nt < 4; ++nt)
                    Pw[qr * QS + nt * 16 + lx] = f2bf(pv[mt][r][nt]);
            }

        // ---- read E fragments; row-sums via ones-MFMA ----------------------
        s16x8 pa[2][2];
        #pragma unroll
        for (int mt = 0; mt < 2; ++mt)
            #pragma unroll
            for (int ks = 0; ks < 2; ++ks)
                pa[mt][ks] = *(const s16x8*)&Pw[(mt * 16 + lx) * QS + ks * 32 + lg * 8];
        f32x4 ssum[2] = {};
        #pragma unroll
        for (int ks = 0; ks < 2; ++ks)
            #pragma unroll
            for (int mt = 0; mt < 2; ++mt)
                ssum[mt] = MFMA16(pa[mt][ks], onesf, ssum[mt]);
        // inv per row; D rows of ssum align with pv rows (lg*4+r)
        float invv[2][4];
        #pragma unroll
        for (int mt = 0; mt < 2; ++mt)
            #pragma unroll
            for (int r = 0; r < 4; ++r) {
                invv[mt][r] = 1.0f / ssum[mt][r];
                const float w8 = invv[mt][r] * 0.125f;
                #pragma unroll
                for (int nt = 0; nt < 4; ++nt)
                    pacc[mt][r][nt] += pv[mt][r][nt] * w8;
            }

        // ---- PV: o = (E V) * inv -------------------------------------------
        s16x8 vb[2][2];
        #pragma unroll
        for (int nt = 0; nt < 2; ++nt)
            #pragma unroll
            for (int ks = 0; ks < 2; ++ks)
                vb[nt][ks] = *(const s16x8*)&VTb[(h * 32 + nt * 16 + lx) * QS + ks * 32 + lg * 8];
        f32x4 oacc[2][2] = {};
        #pragma unroll
        for (int ks = 0; ks < 2; ++ks)
            #pragma unroll
            for (int mt = 0; mt < 2; ++mt)
                #pragma unroll
                for (int nt = 0; nt < 2; ++nt)
                    oacc[mt][nt] = MFMA16(pa[mt][ks], vb[nt][ks], oacc[mt][nt]);
        #pragma unroll
        for (int mt = 0; mt < 2; ++mt)
            #pragma unroll
            for (int nt = 0; nt < 2; ++nt)
                #pragma unroll
                for (int r = 0; r < 4; ++r)
                    ob[(mh * 32 + mt * 16 + lg * 4 + r) * WS +
                       hp * 64 + h * 32 + nt * 16 + lx] =
                        f2bf(oacc[mt][nt][r] * invv[mt][r]);
        __syncthreads();   // b_hp2: Q/K/VT reads done before next hp's QKV
    }

    // ---- attn-mean: h0 waves stage into dead Q/K region --------------------
    if (h == 0) {
        #pragma unroll
        for (int mt = 0; mt < 2; ++mt)
            #pragma unroll
            for (int r = 0; r < 4; ++r) {
                const int row = mh * 32 + mt * 16 + lg * 4 + r;
                #pragma unroll
                for (int nt = 0; nt < 4; ++nt)
                    stg[row * 66 + nt * 16 + lx] = pacc[mt][r][nt];
            }
    }
    // reload afrag from o (winb region)
    #pragma unroll
    for (int mt = 0; mt < 4; ++mt)
        #pragma unroll
        for (int ks = 0; ks < 8; ++ks)
            afrag[mt][ks] = *(const s16x8*)&ob[(lx + mt * 16) * WS + ks * 32 + lg * 8];
    __syncthreads();   // b_stg

    // ---- h1 waves combine + store attention-mean ---------------------------
    if (h == 1) {
        float* abase = aout + (size_t)m * 2401;
        #pragma unroll
        for (int mt = 0; mt < 2; ++mt)
            #pragma unroll
            for (int r = 0; r < 4; ++r) {
                const int q = mh * 32 + mt * 16 + lg * 4 + r;
                if (q < 49) {
                    #pragma unroll
                    for (int nt = 0; nt < 4; ++nt) {
                        const int col = nt * 16 + lx;
                        if (col < 49)
                            abase[q * 49 + col] = stg[q * 66 + col] + pacc[mt][r][nt];
                    }
                }
            }
    }

    // ---- out projection: 4 concurrent nt-chains (pacc/pv/sacc dead here) ---
    float* ybase = yout + (size_t)m * 12544;
    {
        const int n0 = wave * 64;
        const unsigned short* wp0 = wo + (size_t)(n0 +  0 + lx) * 256 + lg * 8;
        const unsigned short* wp1 = wo + (size_t)(n0 + 16 + lx) * 256 + lg * 8;
        const unsigned short* wp2 = wo + (size_t)(n0 + 32 + lx) * 256 + lg * 8;
        const unsigned short* wp3 = wo + (size_t)(n0 + 48 + lx) * 256 + lg * 8;
        f32x4 a0[4] = {}, a1[4] = {}, a2[4] = {}, a3[4] = {};
        #pragma unroll
        for (int ks = 0; ks < 8; ++ks) {
            const s16x8 b0 = *(const s16x8*)(wp0 + ks * 32);
            const s16x8 b1 = *(const s16x8*)(wp1 + ks * 32);
            const s16x8 b2 = *(const s16x8*)(wp2 + ks * 32);
            const s16x8 b3 = *(const s16x8*)(wp3 + ks * 32);
            #pragma unroll
            for (int mt = 0; mt < 4; ++mt) {
                a0[mt] = MFMA16(afrag[mt][ks], b0, a0[mt]);
                a1[mt] = MFMA16(afrag[mt][ks], b1, a1[mt]);
                a2[mt] = MFMA16(afrag[mt][ks], b2, a2[mt]);
                a3[mt] = MFMA16(afrag[mt][ks], b3, a3[mt]);
            }
        }
        const float bias0 = bout[n0 +  0 + lx];
        const float bias1 = bout[n0 + 16 + lx];
        const float bias2 = bout[n0 + 32 + lx];
        const float bias3 = bout[n0 + 48 + lx];
        #pragma unroll
        for (int mt = 0; mt < 4; ++mt) {
            #pragma unroll
            for (int r = 0; r < 4; ++r) {
                const int q = mt * 16 + lg * 4 + r;
                if (q < 49) {
                    ybase[q * 256 + n0 +  0 + lx] = a0[mt][r] + bias0;
                    ybase[q * 256 + n0 + 16 + lx] = a1[mt][r] + bias1;
                    ybase[q * 256 + n0 + 32 + lx] = a2[mt][r] + bias2;
                    ybase[q * 256 + n0 + 48 + lx] = a3[mt][r] + bias3;
                }
            }
        }
    }
}

// ---- weight conversion fp32 -> bf16 ---------------------------------------
__global__ void wmha_cvt_kernel(const float* __restrict__ w_in,
                                const float* __restrict__ w_out,
                                unsigned short* __restrict__ dq,
                                unsigned short* __restrict__ dw)
{
    const int idx = blockIdx.x * 256 + threadIdx.x;
    if (idx < 196608)      dq[idx] = f2bf(w_in[idx]);
    else                   dw[idx - 196608] = f2bf(w_out[idx - 196608]);
}

extern "C" void kernel_launch(void* const* d_in, const int* in_sizes, int n_in,
                              void* d_out, int out_size, void* d_ws, size_t ws_size,
                              hipStream_t stream) {
    const float* x    = (const float*)d_in[0];
    const float* w_in = (const float*)d_in[1];
    const float* b_in = (const float*)d_in[2];
    const float* w_o  = (const float*)d_in[3];
    const float* b_o  = (const float*)d_in[4];

    unsigned short* wq_bf = (unsigned short*)d_ws;
    unsigned short* wo_bf = wq_bf + 196608;

    float* y  = (float*)d_out;
    float* aw = y + (size_t)4096 * 49 * 256;   // 51380224

    wmha_cvt_kernel<<<1024, 256, 0, stream>>>(w_in, w_o, wq_bf, wo_bf);

    hipFuncSetAttribute((const void*)wmha_fused_kernel,
                        hipFuncAttributeMaxDynamicSharedMemorySize, SMEM_BYTES);
    wmha_fused_kernel<<<4096, 256, SMEM_BYTES, stream>>>(
        x, b_in, b_o, wq_bf, wo_bf, y, aw);
}

// Round 18
// 354.805 us; speedup vs baseline: 1.0584x; 1.0059x over previous
//
#include <hip/hip_runtime.h>
#include <hip/hip_bf16.h>

// ---------------------------------------------------------------------------
// WindowsMultiheadAttention: 4096 windows x (L=49, E=256), 8 heads x d=32.
// R18 = R17 (best: 357 us) + register-safe mid-barrier placement:
//   score -> exp (sacc dies) -> E-write -> pa-read -> ones-MFMA -> pacc (pv
//   dies) -> vb-read -> BARRIER -> PV + ob-write + next-hp QKV (unsynced).
// Live across barrier: pa 32 + vb 32 + invv 8 + pacc 32 ~ 104 <= 128 (R16's
// spill came from holding vb across exp's pressure peak; this doesn't).
// Loop-end barrier deleted; same count (2/hp), better placement: slow waves'
// PV tails overlap fast waves' next-QKV B-loads.
// ---------------------------------------------------------------------------

typedef float  f32x4  __attribute__((ext_vector_type(4)));
typedef short  s16x8  __attribute__((ext_vector_type(8)));
typedef short  s16x4  __attribute__((ext_vector_type(4)));

#define MFMA16(a, b, c) __builtin_amdgcn_mfma_f32_16x16x32_bf16((a), (b), (c), 0, 0, 0)

static __device__ __forceinline__ unsigned short f2bf(float f) {
    __hip_bfloat16 h = __float2bfloat16(f);
    unsigned short u;
    __builtin_memcpy(&u, &h, 2);
    return u;
}

// ---- LDS layout (bytes) ----------------------------------------------------
// winb/ob [64][264] bf16 @ 0      (33792)
// Qb      [64][72]  bf16 @ 33792  (9216)
// Kb      [64][72]  bf16 @ 43008  (9216)
// VTb     [64][72]  bf16 @ 52224  (9216)
// Pw      [4][32][72] bf16 @ 61440 (18432)   per-wave private (unnormalized E)
// stg     [64][66]  f32  @ 33792  (16896)    overlays dead Q/K at END
#define SMEM_BYTES 79872
#define WS 264
#define QS 72

__global__ __launch_bounds__(256, 2)
void wmha_fused_kernel(const float* __restrict__ x,
                       const float* __restrict__ bqkv,
                       const float* __restrict__ bout,
                       const unsigned short* __restrict__ wq,   // [768][256] bf16
                       const unsigned short* __restrict__ wo,   // [256][256] bf16
                       float* __restrict__ yout,                // [4096][49][256]
                       float* __restrict__ aout)                // [4096][49][49]
{
    extern __shared__ char smem[];
    unsigned short* winb = (unsigned short*)smem;             // [64][264], later ob
    unsigned short* Qb   = (unsigned short*)(smem + 33792);   // [64][72]
    unsigned short* Kb   = (unsigned short*)(smem + 43008);   // [64][72]
    unsigned short* VTb  = (unsigned short*)(smem + 52224);   // [64][72]
    float* stg = (float*)(smem + 33792);                      // [64][66] f32 (end)

    const int tid  = threadIdx.x;
    const int wave = tid >> 6;
    const int lane = tid & 63;
    const int lx   = lane & 15;
    const int lg   = lane >> 4;
    const int h    = wave & 1;    // head within pair
    const int mh   = wave >> 1;   // M half

    unsigned short* Pw = (unsigned short*)(smem + 61440 + wave * 4608); // [32][72]

    const int m  = blockIdx.x;
    const int b  = m >> 6;
    const int w  = m & 63;
    const int hk = w >> 3;
    const int wk = w & 7;
    const float* xb = x + (size_t)b * 3136 * 256;

    // ---- gather window into LDS (scramble); compile-time unrolled ----------
    #pragma unroll
    for (int ii = 0; ii < 13; ++ii) {
        const int k = tid + ii * 256;
        if (k < 3136) {
            const int p  = k >> 6;
            const int l4 = (k & 63) * 4;
            const int ky = p / 7, kx = p - ky * 7;
            const int rimg = (hk * 7 + ky) * 56 + wk * 7 + kx;
            const float4 v = *(const float4*)&xb[rimg * 256 + l4];
            #pragma unroll
            for (int e = 0; e < 4; ++e) {
                const int j = (l4 + e) * 49 + p;   // l*256+c == c'*49+p
                winb[(j >> 8) * WS + (j & 255)] =
                    f2bf(e == 0 ? v.x : e == 1 ? v.y : e == 2 ? v.z : v.w);
            }
        }
    }
    // zero pad rows 49..63 (vectorized b64)
    #pragma unroll
    for (int ii = 0; ii < 4; ++ii) {
        const int i = tid + ii * 256;         // 960 total
        if (i < 960) {
            const int row = 49 + (i >> 6);
            const int c4  = (i & 63) * 4;
            *(s16x4*)&winb[row * WS + c4] = (s16x4){0, 0, 0, 0};
        }
    }
    __syncthreads();   // b1

    // ---- cache win A-fragments in registers (128 regs) ---------------------
    s16x8 afrag[4][8];
    #pragma unroll
    for (int mt = 0; mt < 4; ++mt)
        #pragma unroll
        for (int ks = 0; ks < 8; ++ks)
            afrag[mt][ks] = *(const s16x8*)&winb[(lx + mt * 16) * WS + ks * 32 + lg * 8];
    __syncthreads();   // b2: winb dead -> region becomes ob

    unsigned short* ob = winb;
    const float scale = 0.17677669529663687f;     // 1/sqrt(32)
    float pacc[2][4][4] = {};                     // [mt][r][nt] attn-mean accum

    // bf16 ones B-fragment for row-sum MFMA (1.0 = 0x3F80)
    s16x8 onesf;
    #pragma unroll
    for (int j = 0; j < 8; ++j) onesf[j] = (short)0x3F80;

    #pragma unroll 1
    for (int hp = 0; hp < 4; ++hp) {
        // ---- QKV projection: this wave's 3 n-tiles (of 12), tile-serial ----
        // (no preceding barrier needed: all Q/K/VT reads of the previous hp
        //  completed before its b_mid; this wave's PV/ob touch Pw/ob only.)
        #pragma unroll
        for (int i = 0; i < 3; ++i) {
            const int t = wave * 3 + i;
            const int part = t >> 2;              // 0=Q 1=K 2=V
            const int sub  = t & 3;               // 16-col chunk of 64-col pair
            const int n0 = part * 256 + hp * 64 + sub * 16;
            f32x4 acc[4] = {};
            const unsigned short* wp = wq + (size_t)(n0 + lx) * 256 + lg * 8;
            #pragma unroll
            for (int ks = 0; ks < 8; ++ks) {
                const s16x8 bb = *(const s16x8*)(wp + ks * 32);
                #pragma unroll
                for (int mt = 0; mt < 4; ++mt)
                    acc[mt] = MFMA16(afrag[mt][ks], bb, acc[mt]);
            }
            const float bias = bqkv[n0 + lx];
            if (part == 0) {
                #pragma unroll
                for (int mt = 0; mt < 4; ++mt)
                    #pragma unroll
                    for (int r = 0; r < 4; ++r)
                        Qb[(mt * 16 + lg * 4 + r) * QS + sub * 16 + lx] =
                            f2bf((acc[mt][r] + bias) * scale);   // pre-scaled Q
            } else if (part == 1) {
                #pragma unroll
                for (int mt = 0; mt < 4; ++mt)
                    #pragma unroll
                    for (int r = 0; r < 4; ++r)
                        Kb[(mt * 16 + lg * 4 + r) * QS + sub * 16 + lx] =
                            f2bf(acc[mt][r] + bias);
            } else {
                #pragma unroll
                for (int mt = 0; mt < 4; ++mt) {  // V^T, packed b64 over tokens
                    s16x4 pk;
                    #pragma unroll
                    for (int r = 0; r < 4; ++r)
                        pk[r] = (short)f2bf(acc[mt][r] + bias);
                    *(s16x4*)&VTb[(sub * 16 + lx) * QS + mt * 16 + lg * 4] = pk;
                }
            }
        }
        __syncthreads();   // b_hp1: Q/K/VT ready

        // ---- scores = (Q*s) K^T for (head h, rows mh*32..+31) --------------
        s16x8 qa[2];
        #pragma unroll
        for (int mt = 0; mt < 2; ++mt)
            qa[mt] = *(const s16x8*)&Qb[(mh * 32 + mt * 16 + lx) * QS + h * 32 + lg * 8];
        f32x4 sacc[2][4] = {};
        #pragma unroll
        for (int nt = 0; nt < 4; ++nt) {
            const s16x8 kb = *(const s16x8*)&Kb[(nt * 16 + lx) * QS + h * 32 + lg * 8];
            #pragma unroll
            for (int mt = 0; mt < 2; ++mt)
                sacc[mt][nt] = MFMA16(qa[mt], kb, sacc[mt][nt]);
        }

        // ---- exp only (no shuffles); E stays UNNORMALIZED (sacc dies) ------
        float pv[2][4][4];
        #pragma unroll
        for (int mt = 0; mt < 2; ++mt) {
            #pragma unroll
            for (int r = 0; r < 4; ++r) {
                const bool ok3 = (lx == 0);       // col 48+lx valid iff lx==0
                pv[mt][r][0] = __expf(sacc[mt][0][r]);
                pv[mt][r][1] = __expf(sacc[mt][1][r]);
                pv[mt][r][2] = __expf(sacc[mt][2][r]);
                pv[mt][r][3] = ok3 ? __expf(sacc[mt][3][r]) : 0.f;
            }
        }

        // ---- write unnormalized E to PRIVATE buffer (no barrier) -----------
        #pragma unroll
        for (int mt = 0; mt < 2; ++mt)
            #pragma unroll
            for (int r = 0; r < 4; ++r) {
                const int qr = mt * 16 + lg * 4 + r;   // local row 0..31
                #pragma unroll
                for (int nt = 0; nt < 4; ++nt)
                    Pw[qr * QS + nt * 16 + lx] = f2bf(pv[mt][r][nt]);
            }

        // ---- read E fragments; row-sums via ones-MFMA; pacc (pv dies) ------
        s16x8 pa[2][2];
        #pragma unroll
        for (int mt = 0; mt < 2; ++mt)
            #pragma unroll
            for (int ks = 0; ks < 2; ++ks)
                pa[mt][ks] = *(const s16x8*)&Pw[(mt * 16 + lx) * QS + ks * 32 + lg * 8];
        f32x4 ssum[2] = {};
        #pragma unroll
        for (int ks = 0; ks < 2; ++ks)
            #pragma unroll
            for (int mt = 0; mt < 2; ++mt)
                ssum[mt] = MFMA16(pa[mt][ks], onesf, ssum[mt]);
        float invv[2][4];
        #pragma unroll
        for (int mt = 0; mt < 2; ++mt)
            #pragma unroll
            for (int r = 0; r < 4; ++r) {
                invv[mt][r] = 1.0f / ssum[mt][r];
                const float w8 = invv[mt][r] * 0.125f;
                #pragma unroll
                for (int nt = 0; nt < 4; ++nt)
                    pacc[mt][r][nt] += pv[mt][r][nt] * w8;
            }

        // ---- last shared read (vb), then the mid barrier -------------------
        s16x8 vb[2][2];
        #pragma unroll
        for (int nt = 0; nt < 2; ++nt)
            #pragma unroll
            for (int ks = 0; ks < 2; ++ks)
                vb[nt][ks] = *(const s16x8*)&VTb[(h * 32 + nt * 16 + lx) * QS + ks * 32 + lg * 8];
        __syncthreads();   // b_mid: ALL Q/K/VT reads done; PV tail + next QKV
                           // run unsynced (live across: pa+vb+invv+pacc ~104)

        // ---- PV: o = (E V) * inv -------------------------------------------
        f32x4 oacc[2][2] = {};
        #pragma unroll
        for (int ks = 0; ks < 2; ++ks)
            #pragma unroll
            for (int mt = 0; mt < 2; ++mt)
                #pragma unroll
                for (int nt = 0; nt < 2; ++nt)
                    oacc[mt][nt] = MFMA16(pa[mt][ks], vb[nt][ks], oacc[mt][nt]);
        #pragma unroll
        for (int mt = 0; mt < 2; ++mt)
            #pragma unroll
            for (int nt = 0; nt < 2; ++nt)
                #pragma unroll
                for (int r = 0; r < 4; ++r)
                    ob[(mh * 32 + mt * 16 + lg * 4 + r) * WS +
                       hp * 64 + h * 32 + nt * 16 + lx] =
                        f2bf(oacc[mt][nt][r] * invv[mt][r]);
        // no loop-end barrier: next QKV writes Q/K/VT, whose reads all
        // completed before b_mid; this tail writes only ob (guarded by b_stg).
    }

    // ---- attn-mean: h0 waves stage into dead Q/K region --------------------
    if (h == 0) {
        #pragma unroll
        for (int mt = 0; mt < 2; ++mt)
            #pragma unroll
            for (int r = 0; r < 4; ++r) {
                const int row = mh * 32 + mt * 16 + lg * 4 + r;
                #pragma unroll
                for (int nt = 0; nt < 4; ++nt)
                    stg[row * 66 + nt * 16 + lx] = pacc[mt][r][nt];
            }
    }
    __syncthreads();   // b_stg: ob complete (all tails) + stg visible

    // reload afrag from o (winb region)
    #pragma unroll
    for (int mt = 0; mt < 4; ++mt)
        #pragma unroll
        for (int ks = 0; ks < 8; ++ks)
            afrag[mt][ks] = *(const s16x8*)&ob[(lx + mt * 16) * WS + ks * 32 + lg * 8];

    // ---- h1 waves combine + store attention-mean ---------------------------
    if (h == 1) {
        float* abase = aout + (size_t)m * 2401;
        #pragma unroll
        for (int mt = 0; mt < 2; ++mt)
            #pragma unroll
            for (int r = 0; r < 4; ++r) {
                const int q = mh * 32 + mt * 16 + lg * 4 + r;
                if (q < 49) {
                    #pragma unroll
                    for (int nt = 0; nt < 4; ++nt) {
                        const int col = nt * 16 + lx;
                        if (col < 49)
                            abase[q * 49 + col] = stg[q * 66 + col] + pacc[mt][r][nt];
                    }
                }
            }
    }

    // ---- out projection: 4 concurrent nt-chains (pacc/pv/sacc dead here) ---
    float* ybase = yout + (size_t)m * 12544;
    {
        const int n0 = wave * 64;
        const unsigned short* wp0 = wo + (size_t)(n0 +  0 + lx) * 256 + lg * 8;
        const unsigned short* wp1 = wo + (size_t)(n0 + 16 + lx) * 256 + lg * 8;
        const unsigned short* wp2 = wo + (size_t)(n0 + 32 + lx) * 256 + lg * 8;
        const unsigned short* wp3 = wo + (size_t)(n0 + 48 + lx) * 256 + lg * 8;
        f32x4 a0[4] = {}, a1[4] = {}, a2[4] = {}, a3[4] = {};
        #pragma unroll
        for (int ks = 0; ks < 8; ++ks) {
            const s16x8 b0 = *(const s16x8*)(wp0 + ks * 32);
            const s16x8 b1 = *(const s16x8*)(wp1 + ks * 32);
            const s16x8 b2 = *(const s16x8*)(wp2 + ks * 32);
            const s16x8 b3 = *(const s16x8*)(wp3 + ks * 32);
            #pragma unroll
            for (int mt = 0; mt < 4; ++mt) {
                a0[mt] = MFMA16(afrag[mt][ks], b0, a0[mt]);
                a1[mt] = MFMA16(afrag[mt][ks], b1, a1[mt]);
                a2[mt] = MFMA16(afrag[mt][ks], b2, a2[mt]);
                a3[mt] = MFMA16(afrag[mt][ks], b3, a3[mt]);
            }
        }
        const float bias0 = bout[n0 +  0 + lx];
        const float bias1 = bout[n0 + 16 + lx];
        const float bias2 = bout[n0 + 32 + lx];
        const float bias3 = bout[n0 + 48 + lx];
        #pragma unroll
        for (int mt = 0; mt < 4; ++mt) {
            #pragma unroll
            for (int r = 0; r < 4; ++r) {
                const int q = mt * 16 + lg * 4 + r;
                if (q < 49) {
                    ybase[q * 256 + n0 +  0 + lx] = a0[mt][r] + bias0;
                    ybase[q * 256 + n0 + 16 + lx] = a1[mt][r] + bias1;
                    ybase[q * 256 + n0 + 32 + lx] = a2[mt][r] + bias2;
                    ybase[q * 256 + n0 + 48 + lx] = a3[mt][r] + bias3;
                }
            }
        }
    }
}

// ---- weight conversion fp32 -> bf16 ---------------------------------------
__global__ void wmha_cvt_kernel(const float* __restrict__ w_in,
                                const float* __restrict__ w_out,
                                unsigned short* __restrict__ dq,
                                unsigned short* __restrict__ dw)
{
    const int idx = blockIdx.x * 256 + threadIdx.x;
    if (idx < 196608)      dq[idx] = f2bf(w_in[idx]);
    else                   dw[idx - 196608] = f2bf(w_out[idx - 196608]);
}

extern "C" void kernel_launch(void* const* d_in, const int* in_sizes, int n_in,
                              void* d_out, int out_size, void* d_ws, size_t ws_size,
                              hipStream_t stream) {
    const float* x    = (const float*)d_in[0];
    const float* w_in = (const float*)d_in[1];
    const float* b_in = (const float*)d_in[2];
    const float* w_o  = (const float*)d_in[3];
    const float* b_o  = (const float*)d_in[4];

    unsigned short* wq_bf = (unsigned short*)d_ws;
    unsigned short* wo_bf = wq_bf + 196608;

    float* y  = (float*)d_out;
    float* aw = y + (size_t)4096 * 49 * 256;   // 51380224

    wmha_cvt_kernel<<<1024, 256, 0, stream>>>(w_in, w_o, wq_bf, wo_bf);

    hipFuncSetAttribute((const void*)wmha_fused_kernel,
                        hipFuncAttributeMaxDynamicSharedMemorySize, SMEM_BYTES);
    wmha_fused_kernel<<<4096, 256, SMEM_BYTES, stream>>>(
        x, b_in, b_o, wq_bf, wo_bf, y, aw);
}